// Round 1
// baseline (333.118 us; speedup 1.0000x reference)
//
#include <hip/hip_runtime.h>
#include <hip/hip_bf16.h>
#include <math.h>

#define B_ 4
#define S_ 2048
#define NH_ 16
#define DH_ 64
#define DM_ 1024

typedef __attribute__((ext_vector_type(4))) float f32x4;
typedef __attribute__((ext_vector_type(8))) short s16x8;

static __device__ __forceinline__ short f2bf(float f) {
  union { float f; unsigned u; } c; c.f = f;
  unsigned r = c.u + 0x7fffu + ((c.u >> 16) & 1u);
  return (short)(r >> 16);
}

static __device__ __forceinline__ void gload16(const void* g, void* l) {
  __builtin_amdgcn_global_load_lds(
      (const __attribute__((address_space(1))) void*)g,
      (__attribute__((address_space(3))) void*)l, 16, 0, 0);
}

// ---------- fp32 -> bf16 convert (n divisible by 2048*8) ----------
__global__ void cvt_kernel(const float* __restrict__ in, short* __restrict__ out) {
  int i = (blockIdx.x * 256 + threadIdx.x) * 8;
  f32x4 a = *(const f32x4*)(in + i);
  f32x4 b = *(const f32x4*)(in + i + 4);
  s16x8 o;
  o[0] = f2bf(a[0]); o[1] = f2bf(a[1]); o[2] = f2bf(a[2]); o[3] = f2bf(a[3]);
  o[4] = f2bf(b[0]); o[5] = f2bf(b[1]); o[6] = f2bf(b[2]); o[7] = f2bf(b[3]);
  *(s16x8*)(out + i) = o;
}

// ---------- transpose+convert: W[k][n] fp32 -> WT[n][k] bf16 (1024x1024) ----------
__global__ void tcvt_kernel(const float* __restrict__ W, short* __restrict__ WT) {
  __shared__ float t[32][33];
  int tx = threadIdx.x & 31, ty = threadIdx.x >> 5;
  int bn = blockIdx.x * 32, bk = blockIdx.y * 32;
#pragma unroll
  for (int r = 0; r < 32; r += 8)
    t[ty + r][tx] = W[(size_t)(bk + ty + r) * DM_ + bn + tx];
  __syncthreads();
#pragma unroll
  for (int r = 0; r < 32; r += 8)
    WT[(size_t)(bn + ty + r) * DM_ + bk + tx] = f2bf(t[tx][ty + r]);
}

// ---------- bf16 GEMM: C[M][1024] = A[M][1024] * BT[1024][1024]^T ----------
// 128x128 tile, BK=64, 4 waves (2x2), 16x16x32 MFMA, XOR-swizzled LDS,
// global_load_lds width 16 with pre-swizzled source addressing.
// EPI 0: write bf16 to Q layout [b,h,s,d]. EPI 1: add bias, write fp32.
template <int EPI>
__global__ __launch_bounds__(256, 2) void gemm_kernel(
    const short* __restrict__ A, const short* __restrict__ BT,
    void* __restrict__ Cout, const float* __restrict__ bias) {
  __shared__ short Al[128 * 64];
  __shared__ short Bl[128 * 64];
  const int tid = threadIdx.x;
  const int wid = tid >> 6, lane = tid & 63;
  const int l15 = lane & 15, l4 = lane >> 4;
  const int bm = blockIdx.y * 128, bn = blockIdx.x * 128;
  const int wm = (wid >> 1) * 64, wn = (wid & 1) * 64;
  f32x4 acc[4][4] = {};

  for (int kt = 0; kt < DM_; kt += 64) {
    __syncthreads();
#pragma unroll
    for (int j = 0; j < 4; ++j) {
      int s = j * 256 + tid;
      int row = s >> 3;
      int sl = (s & 7) ^ (row & 7);  // pre-swizzled source chunk (involution)
      gload16(A + (size_t)(bm + row) * DM_ + kt + sl * 8, &Al[j * 2048 + wid * 512]);
    }
#pragma unroll
    for (int j = 0; j < 4; ++j) {
      int s = j * 256 + tid;
      int row = s >> 3;
      int sl = (s & 7) ^ (row & 7);
      gload16(BT + (size_t)(bn + row) * DM_ + kt + sl * 8, &Bl[j * 2048 + wid * 512]);
    }
    __syncthreads();
#pragma unroll
    for (int kk = 0; kk < 2; ++kk) {
      s16x8 af[4], bfr[4];
#pragma unroll
      for (int mi = 0; mi < 4; ++mi) {
        int row = wm + mi * 16 + l15;
        int sl = (kk * 4 + l4) ^ (row & 7);
        af[mi] = *(const s16x8*)&Al[row * 64 + sl * 8];
      }
#pragma unroll
      for (int ni = 0; ni < 4; ++ni) {
        int row = wn + ni * 16 + l15;
        int sl = (kk * 4 + l4) ^ (row & 7);
        bfr[ni] = *(const s16x8*)&Bl[row * 64 + sl * 8];
      }
#pragma unroll
      for (int mi = 0; mi < 4; ++mi)
#pragma unroll
        for (int ni = 0; ni < 4; ++ni)
          acc[mi][ni] = __builtin_amdgcn_mfma_f32_16x16x32_bf16(af[mi], bfr[ni], acc[mi][ni], 0, 0, 0);
    }
  }

  if (EPI == 0) {
    short* Q = (short*)Cout;
#pragma unroll
    for (int mi = 0; mi < 4; ++mi)
#pragma unroll
      for (int ni = 0; ni < 4; ++ni)
#pragma unroll
        for (int r = 0; r < 4; ++r) {
          int rr = bm + wm + mi * 16 + l4 * 4 + r;
          int cc = bn + wn + ni * 16 + l15;
          int b = rr >> 11, s = rr & 2047, h = cc >> 6, d = cc & 63;
          Q[(((size_t)(b * NH_ + h) * S_ + s) << 6) + d] = f2bf(acc[mi][ni][r]);
        }
  } else {
    float* O = (float*)Cout;
#pragma unroll
    for (int mi = 0; mi < 4; ++mi)
#pragma unroll
      for (int ni = 0; ni < 4; ++ni)
#pragma unroll
        for (int r = 0; r < 4; ++r) {
          int rr = bm + wm + mi * 16 + l4 * 4 + r;
          int cc = bn + wn + ni * 16 + l15;
          O[(size_t)rr * DM_ + cc] = acc[mi][ni][r] + bias[cc];
        }
  }
}

// ---------- causal flash attention, Q=K=V from Qb [bh][s][64] bf16 ----------
// grid: x = q-tile (16), y = bh (64). 4 waves x 32 q-rows. KV tiles of 64.
__global__ __launch_bounds__(256, 2) void attn_kernel(
    const short* __restrict__ Qb, short* __restrict__ Ctx) {
  __shared__ short Kl[64 * 64];       // K tile row-major, XOR-swizzled
  __shared__ short Vt[64 * 64];       // V tile transposed [d][kv], XOR-swizzled
  __shared__ short Pl[4][32 * 64];    // per-wave P, XOR-swizzled
  const int tid = threadIdx.x;
  const int wid = tid >> 6, lane = tid & 63;
  const int l15 = lane & 15, l4 = lane >> 4;
  const int bh = blockIdx.y, qt = blockIdx.x;
  const short* Qh = Qb + (size_t)bh * S_ * DH_;
  const int q0 = qt * 128 + wid * 32;

  s16x8 aq[2][2];
#pragma unroll
  for (int mi = 0; mi < 2; ++mi)
#pragma unroll
    for (int kk = 0; kk < 2; ++kk)
      aq[mi][kk] = *(const s16x8*)(Qh + (size_t)(q0 + mi * 16 + l15) * DH_ + kk * 32 + l4 * 8);

  f32x4 acc_o[2][4] = {};
  float mrow[2][4], lrow[2][4];
#pragma unroll
  for (int mi = 0; mi < 2; ++mi)
#pragma unroll
    for (int r = 0; r < 4; ++r) { mrow[mi][r] = -INFINITY; lrow[mi][r] = 0.f; }

  const int nt = qt * 2 + 2;  // causal: only tiles with kv0 <= q_max
  for (int t = 0; t < nt; ++t) {
    const int kv0 = t * 64;
    __syncthreads();
    // stage K (row-major swizzled) and V^T (transposed swizzled), reg-staged
#pragma unroll
    for (int j = 0; j < 2; ++j) {
      int s = j * 256 + tid;
      int kv = s >> 3, d0 = (s & 7) * 8;
      s16x8 v = *(const s16x8*)(Qh + (size_t)(kv0 + kv) * DH_ + d0);
      int sl = (s & 7) ^ (kv & 7);
      *(s16x8*)&Kl[kv * 64 + sl * 8] = v;
#pragma unroll
      for (int i = 0; i < 8; ++i) {
        int dr = d0 + i;
        Vt[dr * 64 + (((kv >> 3) ^ (dr & 7)) << 3) + (kv & 7)] = v[i];
      }
    }
    __syncthreads();
    // S = Q K^T
    f32x4 sacc[2][4] = {};
#pragma unroll
    for (int kk = 0; kk < 2; ++kk) {
      s16x8 bk[4];
#pragma unroll
      for (int ni = 0; ni < 4; ++ni) {
        int row = ni * 16 + l15;
        int sl = (kk * 4 + l4) ^ (row & 7);
        bk[ni] = *(const s16x8*)&Kl[row * 64 + sl * 8];
      }
#pragma unroll
      for (int mi = 0; mi < 2; ++mi)
#pragma unroll
        for (int ni = 0; ni < 4; ++ni)
          sacc[mi][ni] = __builtin_amdgcn_mfma_f32_16x16x32_bf16(aq[mi][kk], bk[ni], sacc[mi][ni], 0, 0, 0);
    }
    // mask + scale + online softmax (rows live in 16-lane groups)
    float pm[2][4];
#pragma unroll
    for (int mi = 0; mi < 2; ++mi)
#pragma unroll
      for (int r = 0; r < 4; ++r) pm[mi][r] = -INFINITY;
#pragma unroll
    for (int mi = 0; mi < 2; ++mi)
#pragma unroll
      for (int ni = 0; ni < 4; ++ni)
#pragma unroll
        for (int r = 0; r < 4; ++r) {
          int row = q0 + mi * 16 + l4 * 4 + r;
          int col = kv0 + ni * 16 + l15;
          float sv = sacc[mi][ni][r] * 0.125f;
          sv = (col <= row) ? sv : -INFINITY;
          sacc[mi][ni][r] = sv;
          pm[mi][r] = fmaxf(pm[mi][r], sv);
        }
#pragma unroll
    for (int d = 1; d < 16; d <<= 1)
#pragma unroll
      for (int mi = 0; mi < 2; ++mi)
#pragma unroll
        for (int r = 0; r < 4; ++r)
          pm[mi][r] = fmaxf(pm[mi][r], __shfl_xor(pm[mi][r], d, 64));
    float fac[2][4], ps[2][4];
#pragma unroll
    for (int mi = 0; mi < 2; ++mi)
#pragma unroll
      for (int r = 0; r < 4; ++r) {
        float mn = fmaxf(mrow[mi][r], pm[mi][r]);
        fac[mi][r] = __expf(mrow[mi][r] - mn);
        mrow[mi][r] = mn;
        ps[mi][r] = 0.f;
      }
    short* Pw = Pl[wid];
#pragma unroll
    for (int mi = 0; mi < 2; ++mi)
#pragma unroll
      for (int ni = 0; ni < 4; ++ni)
#pragma unroll
        for (int r = 0; r < 4; ++r) {
          float p = __expf(sacc[mi][ni][r] - mrow[mi][r]);
          ps[mi][r] += p;
          int prow = mi * 16 + l4 * 4 + r;
          int pcol = ni * 16 + l15;
          Pw[prow * 64 + (((pcol >> 3) ^ (prow & 7)) << 3) + (pcol & 7)] = f2bf(p);
        }
#pragma unroll
    for (int d = 1; d < 16; d <<= 1)
#pragma unroll
      for (int mi = 0; mi < 2; ++mi)
#pragma unroll
        for (int r = 0; r < 4; ++r)
          ps[mi][r] += __shfl_xor(ps[mi][r], d, 64);
#pragma unroll
    for (int mi = 0; mi < 2; ++mi)
#pragma unroll
      for (int r = 0; r < 4; ++r)
        lrow[mi][r] = lrow[mi][r] * fac[mi][r] + ps[mi][r];
#pragma unroll
    for (int mi = 0; mi < 2; ++mi)
#pragma unroll
      for (int nd = 0; nd < 4; ++nd)
#pragma unroll
        for (int r = 0; r < 4; ++r)
          acc_o[mi][nd][r] *= fac[mi][r];
    __syncthreads();
    // O += P V
#pragma unroll
    for (int kk = 0; kk < 2; ++kk) {
      s16x8 ap[2], bv[4];
#pragma unroll
      for (int mi = 0; mi < 2; ++mi) {
        int prow = mi * 16 + l15;
        ap[mi] = *(const s16x8*)&Pw[prow * 64 + (((kk * 4 + l4) ^ (prow & 7)) << 3)];
      }
#pragma unroll
      for (int nd = 0; nd < 4; ++nd) {
        int row = nd * 16 + l15;
        bv[nd] = *(const s16x8*)&Vt[row * 64 + (((kk * 4 + l4) ^ (row & 7)) << 3)];
      }
#pragma unroll
      for (int mi = 0; mi < 2; ++mi)
#pragma unroll
        for (int nd = 0; nd < 4; ++nd)
          acc_o[mi][nd] = __builtin_amdgcn_mfma_f32_16x16x32_bf16(ap[mi], bv[nd], acc_o[mi][nd], 0, 0, 0);
    }
  }

  const int b = bh >> 4, h = bh & 15;
#pragma unroll
  for (int mi = 0; mi < 2; ++mi)
#pragma unroll
    for (int nd = 0; nd < 4; ++nd)
#pragma unroll
      for (int r = 0; r < 4; ++r) {
        int srow = q0 + mi * 16 + l4 * 4 + r;
        int col = h * 64 + nd * 16 + l15;
        float o = acc_o[mi][nd][r] / lrow[mi][r];
        Ctx[(size_t)(b * S_ + srow) * DM_ + col] = f2bf(o);
      }
}

extern "C" void kernel_launch(void* const* d_in, const int* in_sizes, int n_in,
                              void* d_out, int out_size, void* d_ws, size_t ws_size,
                              hipStream_t stream) {
  const float* x  = (const float*)d_in[0];
  const float* Wq = (const float*)d_in[1];
  const float* Wo = (const float*)d_in[2];
  const float* bo = (const float*)d_in[3];
  float* out = (float*)d_out;
  char* ws = (char*)d_ws;

  short* xb  = (short*)(ws);                    // 16,777,216 B  (x bf16, later reused as ctx)
  short* WqT = (short*)(ws + 16777216);         //  2,097,152 B
  short* WoT = (short*)(ws + 18874368);         //  2,097,152 B
  short* Qb  = (short*)(ws + 20971520);         // 16,777,216 B  ([b,h,s,d] bf16)
  short* Ctx = xb;                              // alias: x dead after GEMM1

  cvt_kernel<<<4096, 256, 0, stream>>>(x, xb);                       // 8.39M elems
  tcvt_kernel<<<dim3(32, 32), 256, 0, stream>>>(Wq, WqT);
  tcvt_kernel<<<dim3(32, 32), 256, 0, stream>>>(Wo, WoT);
  gemm_kernel<0><<<dim3(8, 64), 256, 0, stream>>>(xb, WqT, Qb, nullptr);
  attn_kernel<<<dim3(16, 64), 256, 0, stream>>>(Qb, Ctx);
  gemm_kernel<1><<<dim3(8, 64), 256, 0, stream>>>(Ctx, WoT, out, bo);
}

// Round 2
// 207.810 us; speedup vs baseline: 1.6030x; 1.6030x over previous
//
#include <hip/hip_runtime.h>
#include <hip/hip_bf16.h>
#include <math.h>

#define B_ 4
#define S_ 2048
#define NH_ 16
#define DH_ 64
#define DM_ 1024

typedef __attribute__((ext_vector_type(4))) float f32x4;
typedef __attribute__((ext_vector_type(8))) short s16x8;

static __device__ __forceinline__ short f2bf(float f) {
  union { float f; unsigned u; } c; c.f = f;
  unsigned r = c.u + 0x7fffu + ((c.u >> 16) & 1u);
  return (short)(r >> 16);
}

static __device__ __forceinline__ void gload16(const void* g, void* l) {
  __builtin_amdgcn_global_load_lds(
      (const __attribute__((address_space(1))) void*)g,
      (__attribute__((address_space(3))) void*)l, 16, 0, 0);
}

// ---------- fp32 -> bf16 convert ----------
__global__ void cvt_kernel(const float* __restrict__ in, short* __restrict__ out) {
  int i = (blockIdx.x * 256 + threadIdx.x) * 8;
  f32x4 a = *(const f32x4*)(in + i);
  f32x4 b = *(const f32x4*)(in + i + 4);
  s16x8 o;
  o[0] = f2bf(a[0]); o[1] = f2bf(a[1]); o[2] = f2bf(a[2]); o[3] = f2bf(a[3]);
  o[4] = f2bf(b[0]); o[5] = f2bf(b[1]); o[6] = f2bf(b[2]); o[7] = f2bf(b[3]);
  *(s16x8*)(out + i) = o;
}

// ---------- transpose+convert: W[k][n] fp32 -> WT[n][k] bf16 ----------
__global__ void tcvt_kernel(const float* __restrict__ W, short* __restrict__ WT) {
  __shared__ float t[32][33];
  int tx = threadIdx.x & 31, ty = threadIdx.x >> 5;
  int bn = blockIdx.x * 32, bk = blockIdx.y * 32;
#pragma unroll
  for (int r = 0; r < 32; r += 8)
    t[ty + r][tx] = W[(size_t)(bk + ty + r) * DM_ + bn + tx];
  __syncthreads();
#pragma unroll
  for (int r = 0; r < 32; r += 8)
    WT[(size_t)(bn + ty + r) * DM_ + bk + tx] = f2bf(t[tx][ty + r]);
}

// ---------- bf16 GEMM: C[M][1024] = A[M][1024] * BT[1024][1024]^T ----------
template <int EPI>
__global__ __launch_bounds__(256, 2) void gemm_kernel(
    const short* __restrict__ A, const short* __restrict__ BT,
    void* __restrict__ Cout, const float* __restrict__ bias) {
  __shared__ short Al[128 * 64];
  __shared__ short Bl[128 * 64];
  const int tid = threadIdx.x;
  const int wid = tid >> 6, lane = tid & 63;
  const int l15 = lane & 15, l4 = lane >> 4;
  const int bm = blockIdx.y * 128, bn = blockIdx.x * 128;
  const int wm = (wid >> 1) * 64, wn = (wid & 1) * 64;
  f32x4 acc[4][4] = {};

  for (int kt = 0; kt < DM_; kt += 64) {
    __syncthreads();
#pragma unroll
    for (int j = 0; j < 4; ++j) {
      int s = j * 256 + tid;
      int row = s >> 3;
      int sl = (s & 7) ^ (row & 7);
      gload16(A + (size_t)(bm + row) * DM_ + kt + sl * 8, &Al[j * 2048 + wid * 512]);
    }
#pragma unroll
    for (int j = 0; j < 4; ++j) {
      int s = j * 256 + tid;
      int row = s >> 3;
      int sl = (s & 7) ^ (row & 7);
      gload16(BT + (size_t)(bn + row) * DM_ + kt + sl * 8, &Bl[j * 2048 + wid * 512]);
    }
    __syncthreads();
#pragma unroll
    for (int kk = 0; kk < 2; ++kk) {
      s16x8 af[4], bfr[4];
#pragma unroll
      for (int mi = 0; mi < 4; ++mi) {
        int row = wm + mi * 16 + l15;
        int sl = (kk * 4 + l4) ^ (row & 7);
        af[mi] = *(const s16x8*)&Al[row * 64 + sl * 8];
      }
#pragma unroll
      for (int ni = 0; ni < 4; ++ni) {
        int row = wn + ni * 16 + l15;
        int sl = (kk * 4 + l4) ^ (row & 7);
        bfr[ni] = *(const s16x8*)&Bl[row * 64 + sl * 8];
      }
#pragma unroll
      for (int mi = 0; mi < 4; ++mi)
#pragma unroll
        for (int ni = 0; ni < 4; ++ni)
          acc[mi][ni] = __builtin_amdgcn_mfma_f32_16x16x32_bf16(af[mi], bfr[ni], acc[mi][ni], 0, 0, 0);
    }
  }

  if (EPI == 0) {
    short* Q = (short*)Cout;
#pragma unroll
    for (int mi = 0; mi < 4; ++mi)
#pragma unroll
      for (int ni = 0; ni < 4; ++ni)
#pragma unroll
        for (int r = 0; r < 4; ++r) {
          int rr = bm + wm + mi * 16 + l4 * 4 + r;
          int cc = bn + wn + ni * 16 + l15;
          int b = rr >> 11, s = rr & 2047, h = cc >> 6, d = cc & 63;
          Q[(((size_t)(b * NH_ + h) * S_ + s) << 6) + d] = f2bf(acc[mi][ni][r]);
        }
  } else {
    float* O = (float*)Cout;
#pragma unroll
    for (int mi = 0; mi < 4; ++mi)
#pragma unroll
      for (int ni = 0; ni < 4; ++ni)
#pragma unroll
        for (int r = 0; r < 4; ++r) {
          int rr = bm + wm + mi * 16 + l4 * 4 + r;
          int cc = bn + wn + ni * 16 + l15;
          O[(size_t)rr * DM_ + cc] = acc[mi][ni][r] + bias[cc];
        }
  }
}

// P-store swizzle: octet pairs distinct across l4 groups (write-free) AND
// distinct across 16 consecutive rows (read-free).
#define PSWZ(r) (((r) ^ ((r) >> 2)) & 7)

// ---------- causal flash attention, Q=K=V from Qb [bh][s][64] bf16 ----------
// 1D grid, heavy q-tiles first. Double-buffered K/V, 1 barrier/tile,
// async-stage split, defer-max, conflict-free LDS patterns.
__global__ __launch_bounds__(256, 2) void attn_kernel(
    const short* __restrict__ Qb, short* __restrict__ Ctx) {
  __shared__ short Kl[2][64 * 64];
  __shared__ short Vt[2][64 * 64];
  __shared__ short Pl[4][32 * 64];
  const int tid = threadIdx.x;
  const int wid = tid >> 6, lane = tid & 63;
  const int l15 = lane & 15, l4 = lane >> 4;
  const int bid = blockIdx.x;
  const int qt = 15 - (bid >> 6);        // heavy tiles dispatched first
  const int bh = bid & 63;
  const short* Qh = Qb + (size_t)bh * S_ * DH_;
  const int q0 = qt * 128 + wid * 32;
  const float C = 0.18033688068f;        // 0.125 * log2(e)

  // staging indices: each thread owns 2 chunks of 8 shorts
  const int u = tid & 7;                 // d-chunk within row
  const int kvA = tid >> 3;              // rows 0..31
  const int kvB = 32 + kvA;              // rows 32..63

  // Q fragments (A-operand), held in registers for whole block
  s16x8 aq[2][2];
#pragma unroll
  for (int mi = 0; mi < 2; ++mi)
#pragma unroll
    for (int kk = 0; kk < 2; ++kk)
      aq[mi][kk] = *(const s16x8*)(Qh + (size_t)(q0 + mi * 16 + l15) * DH_ + kk * 32 + l4 * 8);

  f32x4 acc_o[2][4] = {};
  float mrow[2][4], lrow[2][4];
#pragma unroll
  for (int mi = 0; mi < 2; ++mi)
#pragma unroll
    for (int r = 0; r < 4; ++r) { mrow[mi][r] = -INFINITY; lrow[mi][r] = 0.f; }

  auto stage = [&](int c, s16x8 a, s16x8 b) {
    int g7 = kvA & 7;   // == kvB & 7
    *(s16x8*)&Kl[c][kvA * 64 + ((u ^ g7) << 3)] = a;
    *(s16x8*)&Kl[c][kvB * 64 + ((u ^ g7) << 3)] = b;
    int hA = kvA >> 3, hB = kvB >> 3;
#pragma unroll
    for (int i = 0; i < 8; ++i) {
      int ii = i ^ u;                     // stagger: distinct dr&7 per lane in group
      int dr = u * 8 + ii;
      Vt[c][dr * 64 + (((hA ^ (dr & 7)) << 3)) + g7] = a[ii];
      Vt[c][dr * 64 + (((hB ^ (dr & 7)) << 3)) + g7] = b[ii];
    }
  };

  // prologue: stage tile 0 into buffer 0
  {
    s16x8 a = *(const s16x8*)(Qh + (size_t)kvA * DH_ + u * 8);
    s16x8 b = *(const s16x8*)(Qh + (size_t)kvB * DH_ + u * 8);
    stage(0, a, b);
  }

  int c = 0;
  const int nt = qt * 2 + 2;
  for (int t = 0; t < nt; ++t) {
    __syncthreads();                     // publish buf c (single barrier per tile)
    const int kv0 = t * 64;
    const bool nx = (t + 1 < nt);
    s16x8 na, nb;
    if (nx) {                            // issue next tile's loads early (T14)
      int kb = kv0 + 64;
      na = *(const s16x8*)(Qh + (size_t)(kb + kvA) * DH_ + u * 8);
      nb = *(const s16x8*)(Qh + (size_t)(kb + kvB) * DH_ + u * 8);
    }

    if (kv0 <= q0) {                     // wave-uniform: skip tiles above diagonal
      // S = Q K^T
      f32x4 sacc[2][4] = {};
#pragma unroll
      for (int kk = 0; kk < 2; ++kk) {
        s16x8 bk[4];
#pragma unroll
        for (int ni = 0; ni < 4; ++ni) {
          int row = ni * 16 + l15;
          bk[ni] = *(const s16x8*)&Kl[c][row * 64 + (((kk * 4 + l4) ^ (row & 7)) << 3)];
        }
#pragma unroll
        for (int mi = 0; mi < 2; ++mi)
#pragma unroll
          for (int ni = 0; ni < 4; ++ni)
            sacc[mi][ni] = __builtin_amdgcn_mfma_f32_16x16x32_bf16(aq[mi][kk], bk[ni], sacc[mi][ni], 0, 0, 0);
      }
      // row max (raw scores; scale folded into exp2 arg)
      float pm[2][4];
      if (kv0 + 63 > q0) {               // boundary tile: mask
#pragma unroll
        for (int mi = 0; mi < 2; ++mi)
#pragma unroll
          for (int r = 0; r < 4; ++r) pm[mi][r] = -INFINITY;
#pragma unroll
        for (int mi = 0; mi < 2; ++mi)
#pragma unroll
          for (int ni = 0; ni < 4; ++ni)
#pragma unroll
            for (int r = 0; r < 4; ++r) {
              int row = q0 + mi * 16 + l4 * 4 + r;
              int col = kv0 + ni * 16 + l15;
              if (col > row) sacc[mi][ni][r] = -INFINITY;
              pm[mi][r] = fmaxf(pm[mi][r], sacc[mi][ni][r]);
            }
      } else {                           // interior: no masking
#pragma unroll
        for (int mi = 0; mi < 2; ++mi)
#pragma unroll
          for (int r = 0; r < 4; ++r)
            pm[mi][r] = fmaxf(fmaxf(sacc[mi][0][r], sacc[mi][1][r]),
                              fmaxf(sacc[mi][2][r], sacc[mi][3][r]));
      }
#pragma unroll
      for (int d = 1; d < 16; d <<= 1)
#pragma unroll
        for (int mi = 0; mi < 2; ++mi)
#pragma unroll
          for (int r = 0; r < 4; ++r)
            pm[mi][r] = fmaxf(pm[mi][r], __shfl_xor(pm[mi][r], d, 16));

      // defer-max (T13): skip rescale when max growth small
      float need = 0.f;
#pragma unroll
      for (int mi = 0; mi < 2; ++mi)
#pragma unroll
        for (int r = 0; r < 4; ++r)
          need = fmaxf(need, pm[mi][r] - mrow[mi][r]);
      if (!__all(need <= 44.f)) {
        float fac[2][4];
#pragma unroll
        for (int mi = 0; mi < 2; ++mi)
#pragma unroll
          for (int r = 0; r < 4; ++r) {
            float mn = fmaxf(mrow[mi][r], pm[mi][r]);
            fac[mi][r] = exp2f((mrow[mi][r] - mn) * C);
            mrow[mi][r] = mn;
            lrow[mi][r] *= fac[mi][r];
          }
#pragma unroll
        for (int mi = 0; mi < 2; ++mi)
#pragma unroll
          for (int nd = 0; nd < 4; ++nd)
#pragma unroll
            for (int r = 0; r < 4; ++r)
              acc_o[mi][nd][r] *= fac[mi][r];
      }

      // P = exp2((S-m)*C), write to wave-private LDS (conflict-free swizzle)
      float ps[2][4] = {};
      short* Pw = Pl[wid];
#pragma unroll
      for (int mi = 0; mi < 2; ++mi)
#pragma unroll
        for (int ni = 0; ni < 4; ++ni)
#pragma unroll
          for (int r = 0; r < 4; ++r) {
            float p = exp2f((sacc[mi][ni][r] - mrow[mi][r]) * C);
            ps[mi][r] += p;
            int prow = mi * 16 + l4 * 4 + r;
            int pcol = ni * 16 + l15;
            Pw[prow * 64 + (((pcol >> 3) ^ PSWZ(prow)) << 3) + (pcol & 7)] = f2bf(p);
          }
#pragma unroll
      for (int d = 1; d < 16; d <<= 1)
#pragma unroll
        for (int mi = 0; mi < 2; ++mi)
#pragma unroll
          for (int r = 0; r < 4; ++r)
            ps[mi][r] += __shfl_xor(ps[mi][r], d, 16);
#pragma unroll
      for (int mi = 0; mi < 2; ++mi)
#pragma unroll
        for (int r = 0; r < 4; ++r)
          lrow[mi][r] += ps[mi][r];

      // O += P V
#pragma unroll
      for (int kk = 0; kk < 2; ++kk) {
        s16x8 ap[2], bv[4];
#pragma unroll
        for (int mi = 0; mi < 2; ++mi) {
          int pr = mi * 16 + l15;
          ap[mi] = *(const s16x8*)&Pw[pr * 64 + (((kk * 4 + l4) ^ PSWZ(pr)) << 3)];
        }
#pragma unroll
        for (int nd = 0; nd < 4; ++nd) {
          int row = nd * 16 + l15;
          bv[nd] = *(const s16x8*)&Vt[c][row * 64 + (((kk * 4 + l4) ^ (row & 7)) << 3)];
        }
#pragma unroll
        for (int mi = 0; mi < 2; ++mi)
#pragma unroll
          for (int nd = 0; nd < 4; ++nd)
            acc_o[mi][nd] = __builtin_amdgcn_mfma_f32_16x16x32_bf16(ap[mi], bv[nd], acc_o[mi][nd], 0, 0, 0);
      }
    }

    if (nx) stage(c ^ 1, na, nb);        // write next tile after compute
    c ^= 1;
  }

  const int b = bh >> 4, h = bh & 15;
  float inv[2][4];
#pragma unroll
  for (int mi = 0; mi < 2; ++mi)
#pragma unroll
    for (int r = 0; r < 4; ++r) inv[mi][r] = 1.f / lrow[mi][r];
#pragma unroll
  for (int mi = 0; mi < 2; ++mi)
#pragma unroll
    for (int nd = 0; nd < 4; ++nd)
#pragma unroll
      for (int r = 0; r < 4; ++r) {
        int srow = q0 + mi * 16 + l4 * 4 + r;
        int col = h * 64 + nd * 16 + l15;
        Ctx[(size_t)(b * S_ + srow) * DM_ + col] = f2bf(acc_o[mi][nd][r] * inv[mi][r]);
      }
}

extern "C" void kernel_launch(void* const* d_in, const int* in_sizes, int n_in,
                              void* d_out, int out_size, void* d_ws, size_t ws_size,
                              hipStream_t stream) {
  const float* x  = (const float*)d_in[0];
  const float* Wq = (const float*)d_in[1];
  const float* Wo = (const float*)d_in[2];
  const float* bo = (const float*)d_in[3];
  float* out = (float*)d_out;
  char* ws = (char*)d_ws;

  short* xb  = (short*)(ws);
  short* WqT = (short*)(ws + 16777216);
  short* WoT = (short*)(ws + 18874368);
  short* Qb  = (short*)(ws + 20971520);
  short* Ctx = xb;  // alias: x dead after GEMM1

  cvt_kernel<<<4096, 256, 0, stream>>>(x, xb);
  tcvt_kernel<<<dim3(32, 32), 256, 0, stream>>>(Wq, WqT);
  tcvt_kernel<<<dim3(32, 32), 256, 0, stream>>>(Wo, WoT);
  gemm_kernel<0><<<dim3(8, 64), 256, 0, stream>>>(xb, WqT, Qb, nullptr);
  attn_kernel<<<1024, 256, 0, stream>>>(Qb, Ctx);
  gemm_kernel<1><<<dim3(8, 64), 256, 0, stream>>>(Ctx, WoT, out, bo);
}

// Round 3
// 177.422 us; speedup vs baseline: 1.8776x; 1.1713x over previous
//
#include <hip/hip_runtime.h>
#include <hip/hip_bf16.h>
#include <math.h>

#define B_ 4
#define S_ 2048
#define NH_ 16
#define DH_ 64
#define DM_ 1024

typedef __attribute__((ext_vector_type(4))) float f32x4;
typedef __attribute__((ext_vector_type(8))) short s16x8;
typedef __attribute__((ext_vector_type(4))) short s16x4;
typedef __attribute__((ext_vector_type(2))) unsigned u32x2;

static __device__ __forceinline__ short f2bf(float f) {
  union { float f; unsigned u; } c; c.f = f;
  unsigned r = c.u + 0x7fffu + ((c.u >> 16) & 1u);
  return (short)(r >> 16);
}

// packed f32 pair -> bf16x2 (u32, lo=a hi=b); lowers to v_cvt_pk_bf16_f32
static __device__ __forceinline__ unsigned pkbf(float a, float b) {
  union { __hip_bfloat162 h; unsigned u; } cv;
  cv.h = __float22bfloat162_rn(make_float2(a, b));
  return cv.u;
}

static __device__ __forceinline__ s16x4 mk4(unsigned lo, unsigned hi) {
  union { unsigned u[2]; s16x4 v; } x; x.u[0] = lo; x.u[1] = hi; return x.v;
}

#if __has_builtin(__builtin_amdgcn_mfma_f32_16x16x16bf16_1k)
#define HAVE16 1
static __device__ __forceinline__ f32x4 pv_mfma(s16x4 a, s16x4 b, f32x4 c) {
  return __builtin_amdgcn_mfma_f32_16x16x16bf16_1k(a, b, c, 0, 0, 0);
}
#else
#define HAVE16 0
static __device__ __forceinline__ f32x4 pv_mfma(s16x4 a, s16x4 b, f32x4 c) {
  asm volatile("v_mfma_f32_16x16x16_bf16 %0, %1, %2, %0" : "+v"(c) : "v"(a), "v"(b));
  return c;
}
#endif

static __device__ __forceinline__ void gload16(const void* g, void* l) {
  __builtin_amdgcn_global_load_lds(
      (const __attribute__((address_space(1))) void*)g,
      (__attribute__((address_space(3))) void*)l, 16, 0, 0);
}

// ---------- fp32 -> bf16 convert ----------
__global__ void cvt_kernel(const float* __restrict__ in, short* __restrict__ out) {
  int i = (blockIdx.x * 256 + threadIdx.x) * 8;
  f32x4 a = *(const f32x4*)(in + i);
  f32x4 b = *(const f32x4*)(in + i + 4);
  s16x8 o;
  o[0] = f2bf(a[0]); o[1] = f2bf(a[1]); o[2] = f2bf(a[2]); o[3] = f2bf(a[3]);
  o[4] = f2bf(b[0]); o[5] = f2bf(b[1]); o[6] = f2bf(b[2]); o[7] = f2bf(b[3]);
  *(s16x8*)(out + i) = o;
}

// ---------- transpose+convert: W[k][n] fp32 -> WT[n][k] bf16 ----------
__global__ void tcvt_kernel(const float* __restrict__ W, short* __restrict__ WT) {
  __shared__ float t[32][33];
  int tx = threadIdx.x & 31, ty = threadIdx.x >> 5;
  int bn = blockIdx.x * 32, bk = blockIdx.y * 32;
#pragma unroll
  for (int r = 0; r < 32; r += 8)
    t[ty + r][tx] = W[(size_t)(bk + ty + r) * DM_ + bn + tx];
  __syncthreads();
#pragma unroll
  for (int r = 0; r < 32; r += 8)
    WT[(size_t)(bn + ty + r) * DM_ + bk + tx] = f2bf(t[tx][ty + r]);
}

// ---------- bf16 GEMM: C[M][1024] = A[M][1024] * BT[1024][1024]^T ----------
template <int EPI>
__global__ __launch_bounds__(256, 2) void gemm_kernel(
    const short* __restrict__ A, const short* __restrict__ BT,
    void* __restrict__ Cout, const float* __restrict__ bias) {
  __shared__ short Al[128 * 64];
  __shared__ short Bl[128 * 64];
  const int tid = threadIdx.x;
  const int wid = tid >> 6, lane = tid & 63;
  const int l15 = lane & 15, l4 = lane >> 4;
  const int bm = blockIdx.y * 128, bn = blockIdx.x * 128;
  const int wm = (wid >> 1) * 64, wn = (wid & 1) * 64;
  f32x4 acc[4][4] = {};

  for (int kt = 0; kt < DM_; kt += 64) {
    __syncthreads();
#pragma unroll
    for (int j = 0; j < 4; ++j) {
      int s = j * 256 + tid;
      int row = s >> 3;
      int sl = (s & 7) ^ (row & 7);
      gload16(A + (size_t)(bm + row) * DM_ + kt + sl * 8, &Al[j * 2048 + wid * 512]);
    }
#pragma unroll
    for (int j = 0; j < 4; ++j) {
      int s = j * 256 + tid;
      int row = s >> 3;
      int sl = (s & 7) ^ (row & 7);
      gload16(BT + (size_t)(bn + row) * DM_ + kt + sl * 8, &Bl[j * 2048 + wid * 512]);
    }
    __syncthreads();
#pragma unroll
    for (int kk = 0; kk < 2; ++kk) {
      s16x8 af[4], bfr[4];
#pragma unroll
      for (int mi = 0; mi < 4; ++mi) {
        int row = wm + mi * 16 + l15;
        int sl = (kk * 4 + l4) ^ (row & 7);
        af[mi] = *(const s16x8*)&Al[row * 64 + sl * 8];
      }
#pragma unroll
      for (int ni = 0; ni < 4; ++ni) {
        int row = wn + ni * 16 + l15;
        int sl = (kk * 4 + l4) ^ (row & 7);
        bfr[ni] = *(const s16x8*)&Bl[row * 64 + sl * 8];
      }
#pragma unroll
      for (int mi = 0; mi < 4; ++mi)
#pragma unroll
        for (int ni = 0; ni < 4; ++ni)
          acc[mi][ni] = __builtin_amdgcn_mfma_f32_16x16x32_bf16(af[mi], bfr[ni], acc[mi][ni], 0, 0, 0);
    }
  }

  if (EPI == 0) {
    short* Q = (short*)Cout;
#pragma unroll
    for (int mi = 0; mi < 4; ++mi)
#pragma unroll
      for (int ni = 0; ni < 4; ++ni)
#pragma unroll
        for (int r = 0; r < 4; ++r) {
          int rr = bm + wm + mi * 16 + l4 * 4 + r;
          int cc = bn + wn + ni * 16 + l15;
          int b = rr >> 11, s = rr & 2047, h = cc >> 6, d = cc & 63;
          Q[(((size_t)(b * NH_ + h) * S_ + s) << 6) + d] = f2bf(acc[mi][ni][r]);
        }
  } else {
    float* O = (float*)Cout;
#pragma unroll
    for (int mi = 0; mi < 4; ++mi)
#pragma unroll
      for (int ni = 0; ni < 4; ++ni)
#pragma unroll
        for (int r = 0; r < 4; ++r) {
          int rr = bm + wm + mi * 16 + l4 * 4 + r;
          int cc = bn + wn + ni * 16 + l15;
          O[(size_t)rr * DM_ + cc] = acc[mi][ni][r] + bias[cc];
        }
  }
}

// ---------- causal flash attention, Q=K=V from Qb [bh][s][64] bf16 ----------
// Swapped-operand S^T = mfma(K,Q): each lane owns q=l15, 16 k's in-register.
// Softmax fully lane-local (2 shfl per reduce). P feeds PV's 16x16x16 MFMA
// B-operand directly from registers (k = l4*4+i matches S^T layout) -> no
// P LDS round-trip. O accumulated transposed (O^T[d][q]).
__global__ __launch_bounds__(256, 2) void attn_kernel(
    const short* __restrict__ Qb, short* __restrict__ Ctx) {
  __shared__ short Kl[2][64 * 64];
  __shared__ short Vt[2][64 * 64];
  const int tid = threadIdx.x;
  const int wid = tid >> 6, lane = tid & 63;
  const int l15 = lane & 15, l4 = lane >> 4;
  const int bid = blockIdx.x;
  const int qt = 15 - (bid >> 6);        // heavy tiles dispatched first
  const int bh = bid & 63;
  const short* Qh = Qb + (size_t)bh * S_ * DH_;
  const int q0 = qt * 128 + wid * 32;
  const float C = 0.18033688068f;        // 0.125 * log2(e)

  const int u = tid & 7;
  const int kvA = tid >> 3;
  const int kvB = 32 + kvA;

  // Q fragments (B-operand of S^T): lane l15 = q-row, d = kk*32 + l4*8..+7
  s16x8 aq[2][2];
#pragma unroll
  for (int qi = 0; qi < 2; ++qi)
#pragma unroll
    for (int kk = 0; kk < 2; ++kk)
      aq[qi][kk] = *(const s16x8*)(Qh + (size_t)(q0 + qi * 16 + l15) * DH_ + kk * 32 + l4 * 8);

  f32x4 acc_o[4][2] = {};                // O^T: [d-frag][q-frag]
  float mrow[2] = {-INFINITY, -INFINITY};
  float lrow[2] = {0.f, 0.f};
  float mC[2]   = {-INFINITY, -INFINITY};

  auto stage = [&](int c, s16x8 a, s16x8 b) {
    int g7 = kvA & 7;
    *(s16x8*)&Kl[c][kvA * 64 + ((u ^ g7) << 3)] = a;
    *(s16x8*)&Kl[c][kvB * 64 + ((u ^ g7) << 3)] = b;
    int hA = kvA >> 3, hB = kvB >> 3;
#pragma unroll
    for (int i = 0; i < 8; ++i) {
      int ii = i ^ u;
      int dr = u * 8 + ii;
      Vt[c][dr * 64 + (((hA ^ (dr & 7)) << 3)) + g7] = a[ii];
      Vt[c][dr * 64 + (((hB ^ (dr & 7)) << 3)) + g7] = b[ii];
    }
  };

  {
    s16x8 a = *(const s16x8*)(Qh + (size_t)kvA * DH_ + u * 8);
    s16x8 b = *(const s16x8*)(Qh + (size_t)kvB * DH_ + u * 8);
    stage(0, a, b);
  }

  int c = 0;
  const int nt = qt * 2 + 2;
  for (int t = 0; t < nt; ++t) {
    __syncthreads();
    const int kv0 = t * 64;
    const bool nx = (t + 1 < nt);
    s16x8 na, nb;
    if (nx) {
      int kb = kv0 + 64;
      na = *(const s16x8*)(Qh + (size_t)(kb + kvA) * DH_ + u * 8);
      nb = *(const s16x8*)(Qh + (size_t)(kb + kvB) * DH_ + u * 8);
    }

    if (kv0 <= q0) {
      // S^T[kv][q] = mfma(A = K-rows, B = Q-rows)
      f32x4 sa[4][2] = {};
#pragma unroll
      for (int kk = 0; kk < 2; ++kk) {
        s16x8 ka[4];
#pragma unroll
        for (int ki = 0; ki < 4; ++ki) {
          int row = ki * 16 + l15;
          ka[ki] = *(const s16x8*)&Kl[c][row * 64 + (((kk * 4 + l4) ^ (row & 7)) << 3)];
        }
#pragma unroll
        for (int ki = 0; ki < 4; ++ki)
#pragma unroll
          for (int qi = 0; qi < 2; ++qi)
            sa[ki][qi] = __builtin_amdgcn_mfma_f32_16x16x32_bf16(ka[ki], aq[qi][kk], sa[ki][qi], 0, 0, 0);
      }

      if (kv0 + 63 > q0) {               // boundary: causal mask (kv > q)
#pragma unroll
        for (int ki = 0; ki < 4; ++ki)
#pragma unroll
          for (int qi = 0; qi < 2; ++qi)
#pragma unroll
            for (int r = 0; r < 4; ++r) {
              int kvg = kv0 + ki * 16 + l4 * 4 + r;
              int qg = q0 + qi * 16 + l15;
              if (kvg > qg) sa[ki][qi][r] = -INFINITY;
            }
      }

      // per-q max: 16 in-lane values, then 2 shfl across l4 groups
      float pm[2];
#pragma unroll
      for (int qi = 0; qi < 2; ++qi) {
        float m0 = fmaxf(fmaxf(sa[0][qi][0], sa[0][qi][1]), fmaxf(sa[0][qi][2], sa[0][qi][3]));
        float m1 = fmaxf(fmaxf(sa[1][qi][0], sa[1][qi][1]), fmaxf(sa[1][qi][2], sa[1][qi][3]));
        float m2 = fmaxf(fmaxf(sa[2][qi][0], sa[2][qi][1]), fmaxf(sa[2][qi][2], sa[2][qi][3]));
        float m3 = fmaxf(fmaxf(sa[3][qi][0], sa[3][qi][1]), fmaxf(sa[3][qi][2], sa[3][qi][3]));
        float m = fmaxf(fmaxf(m0, m1), fmaxf(m2, m3));
        m = fmaxf(m, __shfl_xor(m, 16, 64));
        m = fmaxf(m, __shfl_xor(m, 32, 64));
        pm[qi] = m;
      }

      // defer-max (T13)
      float need = fmaxf(pm[0] - mrow[0], pm[1] - mrow[1]);
      if (!__all(need <= 44.f)) {
        float fac[2];
#pragma unroll
        for (int qi = 0; qi < 2; ++qi) {
          float mn = fmaxf(mrow[qi], pm[qi]);
          fac[qi] = exp2f((mrow[qi] - mn) * C);
          mrow[qi] = mn;
          mC[qi] = mn * C;
          lrow[qi] *= fac[qi];
        }
#pragma unroll
        for (int df = 0; df < 4; ++df)
#pragma unroll
          for (int qi = 0; qi < 2; ++qi)
#pragma unroll
            for (int r = 0; r < 4; ++r)
              acc_o[df][qi][r] *= fac[qi];
      }

      // P = exp2(S*C - m*C), lane-local; pack to bf16 pairs for PV B-operand
      unsigned pw[4][2][2];
      float srow[2] = {0.f, 0.f};
#pragma unroll
      for (int ki = 0; ki < 4; ++ki)
#pragma unroll
        for (int qi = 0; qi < 2; ++qi) {
          float e0 = exp2f(fmaf(sa[ki][qi][0], C, -mC[qi]));
          float e1 = exp2f(fmaf(sa[ki][qi][1], C, -mC[qi]));
          float e2 = exp2f(fmaf(sa[ki][qi][2], C, -mC[qi]));
          float e3 = exp2f(fmaf(sa[ki][qi][3], C, -mC[qi]));
          srow[qi] += (e0 + e1) + (e2 + e3);
          pw[ki][qi][0] = pkbf(e0, e1);
          pw[ki][qi][1] = pkbf(e2, e3);
        }
#pragma unroll
      for (int qi = 0; qi < 2; ++qi) {
        float s = srow[qi];
        s += __shfl_xor(s, 16, 64);
        s += __shfl_xor(s, 32, 64);
        lrow[qi] += s;
      }

      // O^T += V^T · P  (16x16x16: A = Vt rows d, B = P rows q, k = kv)
#pragma unroll
      for (int df = 0; df < 4; ++df) {
        int dr = df * 16 + l15;
#pragma unroll
        for (int ki = 0; ki < 4; ++ki) {
          int grp = ki * 2 + (l4 >> 1);
          s16x4 av = *(const s16x4*)&Vt[c][dr * 64 + ((grp ^ (dr & 7)) << 3) + (l4 & 1) * 4];
#pragma unroll
          for (int qi = 0; qi < 2; ++qi)
            acc_o[df][qi] = pv_mfma(av, mk4(pw[ki][qi][0], pw[ki][qi][1]), acc_o[df][qi]);
        }
      }
#if !HAVE16
      asm volatile("s_nop 7" :::);
      asm volatile("s_nop 7" :::);
#endif
    }

    if (nx) stage(c ^ 1, na, nb);
    c ^= 1;
  }

  const int b = bh >> 4, h = bh & 15;
  float inv[2] = {1.f / lrow[0], 1.f / lrow[1]};
#pragma unroll
  for (int df = 0; df < 4; ++df)
#pragma unroll
    for (int qi = 0; qi < 2; ++qi) {
      int qg = q0 + qi * 16 + l15;
      int col = h * 64 + df * 16 + l4 * 4;
      u32x2 pk;
      pk[0] = pkbf(acc_o[df][qi][0] * inv[qi], acc_o[df][qi][1] * inv[qi]);
      pk[1] = pkbf(acc_o[df][qi][2] * inv[qi], acc_o[df][qi][3] * inv[qi]);
      *(u32x2*)&Ctx[(size_t)(b * S_ + qg) * DM_ + col] = pk;
    }
}

extern "C" void kernel_launch(void* const* d_in, const int* in_sizes, int n_in,
                              void* d_out, int out_size, void* d_ws, size_t ws_size,
                              hipStream_t stream) {
  const float* x  = (const float*)d_in[0];
  const float* Wq = (const float*)d_in[1];
  const float* Wo = (const float*)d_in[2];
  const float* bo = (const float*)d_in[3];
  float* out = (float*)d_out;
  char* ws = (char*)d_ws;

  short* xb  = (short*)(ws);
  short* WqT = (short*)(ws + 16777216);
  short* WoT = (short*)(ws + 18874368);
  short* Qb  = (short*)(ws + 20971520);
  short* Ctx = xb;  // alias: x dead after GEMM1

  cvt_kernel<<<4096, 256, 0, stream>>>(x, xb);
  tcvt_kernel<<<dim3(32, 32), 256, 0, stream>>>(Wq, WqT);
  tcvt_kernel<<<dim3(32, 32), 256, 0, stream>>>(Wo, WoT);
  gemm_kernel<0><<<dim3(8, 64), 256, 0, stream>>>(xb, WqT, Qb, nullptr);
  attn_kernel<<<1024, 256, 0, stream>>>(Qb, Ctx);
  gemm_kernel<1><<<dim3(8, 64), 256, 0, stream>>>(Ctx, WoT, out, bo);
}